// Round 2
// baseline (966.266 us; speedup 1.0000x reference)
//
#include <hip/hip_runtime.h>

#define N_    64
#define CIN   192
#define COUT  192
#define H_    64
#define W_    64
#define BN_EPS 1e-5f
#define M_    262144.0f              // N*H*W
#define SYT_STRIDE 200               // bf16 elems per pixel row (192 + 8 pad)

typedef __attribute__((ext_vector_type(8))) short  short8;
typedef __attribute__((ext_vector_type(4))) float  floatx4;

__device__ __forceinline__ unsigned short f2bf(float f) {
    union { float f; unsigned int u; } v; v.f = f;
    unsigned int u = v.u;
    return (unsigned short)((u + 0x7FFFu + ((u >> 16) & 1u)) >> 16);  // RNE
}

// ---------------------------------------------------------------------------
// Init: blocks 0..143 convert pw fp32 -> bf16 (36864 elems); block 144 zeros
// BN accumulators ws[0..383].
// ---------------------------------------------------------------------------
__global__ __launch_bounds__(256) void init_ws(
    const float* __restrict__ pw, float* __restrict__ ws,
    unsigned short* __restrict__ pwb)
{
    const int b = blockIdx.x, t = threadIdx.x;
    if (b < 144) {
        const int i = b * 256 + t;
        pwb[i] = f2bf(pw[i]);
    } else {
        for (int i = t; i < 384; i += 256) ws[i] = 0.f;
    }
}

// ---------------------------------------------------------------------------
// K1: ReLU + depthwise dilated conv -> y bf16 NHWC [n][h][w][c].
// One block per (n,h) row, 256 threads. Taps via shfl: 1 load + 2 shfl / row.
// XCD-swizzled so each XCD gets 8 contiguous images (h-row reuse in its L2).
// No MFMA, 6.9 KB LDS -> full 32-wave occupancy.
// ---------------------------------------------------------------------------
__global__ __launch_bounds__(256) void dw_kernel(
    const float* __restrict__ x, const float* __restrict__ dww,
    unsigned short* __restrict__ y)
{
    __shared__ float sdw[CIN * 9];                // 6.9 KB

    const int t   = threadIdx.x;
    const int bid = blockIdx.x;
    const int wg  = ((bid & 7) << 9) | (bid >> 3);   // bijective, 4096 % 8 == 0
    const int n   = wg >> 6;
    const int h   = wg & 63;

    for (int i = t; i < CIN * 9; i += 256) sdw[i] = dww[i];

    const int  w    = t & 63;                     // wave = lanes w 0..63 exactly
    const int  cblk = t >> 6;                     // wave id 0..3
    const bool wm0  = (w >= 2);
    const bool wm2  = (w <= 61);
    __syncthreads();

    const int h0 = h - 2;
    for (int e = 0; e < 6; ++e) {
        const int cb = (cblk + (e << 2)) << 3;    // channel base (multiple of 8)
        float a[8];
        #pragma unroll
        for (int ci = 0; ci < 8; ++ci) {
            const int c = cb + ci;
            const float* xp = x + (((size_t)(n * CIN + c)) << 12) + w;
            const float* kw = &sdw[c * 9];
            float acc = 0.f;
            #pragma unroll
            for (int dh = 0; dh < 3; ++dh) {
                const int hh = h0 + (dh << 1);
                if ((unsigned)hh < 64u) {         // uniform per block
                    float v1 = fmaxf(xp[hh << 6], 0.f);
                    float v0 = __shfl_up(v1, 2, 64);   // lane w-2's center
                    float v2 = __shfl_down(v1, 2, 64); // lane w+2's center
                    v0 = wm0 ? v0 : 0.f;
                    v2 = wm2 ? v2 : 0.f;
                    acc = fmaf(v0, kw[3 * dh + 0], acc);
                    acc = fmaf(v1, kw[3 * dh + 1], acc);
                    acc = fmaf(v2, kw[3 * dh + 2], acc);
                }
            }
            a[ci] = acc;
        }
        uint4 pk;
        pk.x = (unsigned)f2bf(a[0]) | ((unsigned)f2bf(a[1]) << 16);
        pk.y = (unsigned)f2bf(a[2]) | ((unsigned)f2bf(a[3]) << 16);
        pk.z = (unsigned)f2bf(a[4]) | ((unsigned)f2bf(a[5]) << 16);
        pk.w = (unsigned)f2bf(a[6]) | ((unsigned)f2bf(a[7]) << 16);
        *(uint4*)&y[(size_t)wg * 12288 + (size_t)w * 192 + cb] = pk;
    }
}

// ---------------------------------------------------------------------------
// K2: pointwise GEMM (bf16 MFMA) + z store + BN stats.
// One block per (n,h): stage contiguous 24 KB y-tile -> padded LDS, then the
// proven phase-2 MFMA loop against precomputed bf16 pw. One barrier total.
// ---------------------------------------------------------------------------
__global__ __launch_bounds__(256) void gemm_kernel(
    const unsigned short* __restrict__ y, const unsigned short* __restrict__ pwb,
    float* __restrict__ zout, float* __restrict__ ws)
{
    __shared__ unsigned short syT[W_ * SYT_STRIDE]; // 25.6 KB [pix][c] bf16

    const int t  = threadIdx.x;
    const int wg = blockIdx.x;                    // n*64 + h
    const int n  = wg >> 6;
    const int h  = wg & 63;

    // ---- Stage y tile (contiguous 1536 x 16B) into padded LDS ----
    const size_t ybase = (size_t)wg * 12288;
    #pragma unroll
    for (int it = 0; it < 6; ++it) {
        const int idx = it * 256 + t;             // 0..1535
        const int px  = idx / 24;                 // 24 chunks per 192-elem row
        const int cb  = (idx % 24) << 3;
        uint4 v = *(const uint4*)&y[ybase + (size_t)idx * 8];
        *(uint4*)&syT[px * SYT_STRIDE + cb] = v;
    }
    __syncthreads();

    // ---- MFMA: wave wv owns o in [48wv, 48wv+48), all 64 pixels ----
    const int wv   = t >> 6;
    const int lane = t & 63;
    const int l15  = lane & 15;
    const int q    = lane >> 4;                   // quad 0..3
    const int ob   = wv * 48;

    floatx4 acc[3][4];
    #pragma unroll
    for (int mt = 0; mt < 3; ++mt)
        #pragma unroll
        for (int nt = 0; nt < 4; ++nt) acc[mt][nt] = (floatx4)0.f;

    #pragma unroll
    for (int kk = 0; kk < 6; ++kk) {
        const int k0 = kk * 32 + q * 8;           // lane's 8 k-elements

        short8 af[3];
        #pragma unroll
        for (int mt = 0; mt < 3; ++mt)
            af[mt] = *(const short8*)&pwb[(size_t)(ob + mt * 16 + l15) * CIN + k0];

        short8 bf[4];
        #pragma unroll
        for (int nt = 0; nt < 4; ++nt)
            bf[nt] = *(const short8*)&syT[(nt * 16 + l15) * SYT_STRIDE + k0];

        #pragma unroll
        for (int mt = 0; mt < 3; ++mt)
            #pragma unroll
            for (int nt = 0; nt < 4; ++nt)
                acc[mt][nt] = __builtin_amdgcn_mfma_f32_16x16x32_bf16(
                    af[mt], bf[nt], acc[mt][nt], 0, 0, 0);
    }

    // ---- Epilogue: store z (row o = q*4+r, col pix = l15) + stats ----
    const size_t base = (((size_t)n * COUT) << 12) + ((size_t)h << 6);
    #pragma unroll
    for (int mt = 0; mt < 3; ++mt) {
        #pragma unroll
        for (int r = 0; r < 4; ++r) {
            const int o = ob + mt * 16 + q * 4 + r;
            float s = 0.f, ss = 0.f;
            #pragma unroll
            for (int nt = 0; nt < 4; ++nt) {
                const float v = acc[mt][nt][r];
                zout[base + ((size_t)o << 12) + nt * 16 + l15] = v;
                s  += v;
                ss += v * v;
            }
            #pragma unroll
            for (int off = 8; off > 0; off >>= 1) {
                s  += __shfl_down(s,  off, 16);
                ss += __shfl_down(ss, off, 16);
            }
            if (l15 == 0) {
                atomicAdd(&ws[o], s);
                atomicAdd(&ws[COUT + o], ss);
            }
        }
    }
}

// ---------------------------------------------------------------------------
// Stats fold: sums -> per-channel scale/shift
// ---------------------------------------------------------------------------
__global__ __launch_bounds__(256) void stats_kernel(
    const float* __restrict__ gamma, const float* __restrict__ beta,
    float* __restrict__ ws)
{
    int t = threadIdx.x;
    if (t < COUT) {
        const float invM = 1.0f / M_;
        float m    = ws[t] * invM;
        float v    = ws[COUT + t] * invM - m * m;
        float rstd = rsqrtf(v + BN_EPS);
        float sc   = gamma[t] * rstd;
        ws[2 * COUT + t] = sc;
        ws[3 * COUT + t] = beta[t] - m * sc;
    }
}

// ---------------------------------------------------------------------------
// Norm: one block per (n,c) plane -> scale/shift are block-uniform (scalar),
// 4 float4 per thread, fully coalesced, in place.
// ---------------------------------------------------------------------------
__global__ __launch_bounds__(256) void norm2_kernel(
    float* __restrict__ out, const float* __restrict__ ws)
{
    const int p = blockIdx.x;                     // n*COUT + c
    const int c = p % COUT;
    const float sc = ws[2 * COUT + c];
    const float sh = ws[3 * COUT + c];
    float4* o4 = (float4*)out + (size_t)p * 1024; // 1024 float4 per plane
    #pragma unroll
    for (int i = 0; i < 4; ++i) {
        float4 v = o4[threadIdx.x + (i << 8)];
        v.x = fmaf(v.x, sc, sh);
        v.y = fmaf(v.y, sc, sh);
        v.z = fmaf(v.z, sc, sh);
        v.w = fmaf(v.w, sc, sh);
        o4[threadIdx.x + (i << 8)] = v;
    }
}

// ===========================================================================
// Fallback path (verified previous kernel) — used only if ws_size is too
// small for the y workspace.
// ===========================================================================
__global__ __launch_bounds__(384) void zero_ws(float* __restrict__ ws) {
    int t = threadIdx.x;
    if (t < 384) ws[t] = 0.f;
}

__global__ __launch_bounds__(256, 4) void fused_kernel(
    const float* __restrict__ x, const float* __restrict__ dww,
    const float* __restrict__ pw, float* __restrict__ zout,
    float* __restrict__ ws)
{
    __shared__ float  sdw[CIN * 9];
    __shared__ unsigned short syT[W_ * SYT_STRIDE];

    const int t = threadIdx.x;
    const int n = blockIdx.x >> 6;
    const int h = blockIdx.x & 63;

    for (int i = t; i < CIN * 9; i += 256) sdw[i] = dww[i];

    const int  w    = t & 63;
    const int  cblk = t >> 6;
    const bool wm0  = (w >= 2);
    const bool wm2  = (w <= 61);
    const int  om   = wm0 ? -2 : 0;
    const int  op   = wm2 ?  2 : 0;
    __syncthreads();

    for (int e = 0; e < 6; ++e) {
        const int cb = (cblk + (e << 2)) << 3;
        float a[8];
        #pragma unroll
        for (int ci = 0; ci < 8; ++ci) {
            const int c = cb + ci;
            const float* xr0 = x + (((size_t)(n * CIN + c)) << 12) + w;
            const float* kw  = &sdw[c * 9];
            float acc = 0.f;
            #pragma unroll
            for (int dh = 0; dh < 3; ++dh) {
                const int hh = h + 2 * dh - 2;
                if ((unsigned)hh < 64u) {
                    const float* xr = xr0 + (hh << 6);
                    float v0 = fmaxf(xr[om], 0.f);
                    float v1 = fmaxf(xr[0],  0.f);
                    float v2 = fmaxf(xr[op], 0.f);
                    v0 = wm0 ? v0 : 0.f;
                    v2 = wm2 ? v2 : 0.f;
                    acc = fmaf(v0, kw[3 * dh + 0], acc);
                    acc = fmaf(v1, kw[3 * dh + 1], acc);
                    acc = fmaf(v2, kw[3 * dh + 2], acc);
                }
            }
            a[ci] = acc;
        }
        uint4 pk;
        pk.x = (unsigned)f2bf(a[0]) | ((unsigned)f2bf(a[1]) << 16);
        pk.y = (unsigned)f2bf(a[2]) | ((unsigned)f2bf(a[3]) << 16);
        pk.z = (unsigned)f2bf(a[4]) | ((unsigned)f2bf(a[5]) << 16);
        pk.w = (unsigned)f2bf(a[6]) | ((unsigned)f2bf(a[7]) << 16);
        *(uint4*)&syT[w * SYT_STRIDE + cb] = pk;
    }
    __syncthreads();

    const int wv   = t >> 6;
    const int lane = t & 63;
    const int l15  = lane & 15;
    const int q    = lane >> 4;
    const int ob   = wv * 48;

    floatx4 acc[3][4];
    #pragma unroll
    for (int mt = 0; mt < 3; ++mt)
        #pragma unroll
        for (int nt = 0; nt < 4; ++nt) acc[mt][nt] = (floatx4)0.f;

    #pragma unroll
    for (int kk = 0; kk < 6; ++kk) {
        const int k0 = kk * 32 + q * 8;

        short8 af[3];
        #pragma unroll
        for (int mt = 0; mt < 3; ++mt) {
            const float4* ap = (const float4*)(pw + (size_t)(ob + mt * 16 + l15) * CIN + k0);
            float4 u = ap[0];
            float4 v = ap[1];
            short8 f;
            f[0] = (short)f2bf(u.x); f[1] = (short)f2bf(u.y);
            f[2] = (short)f2bf(u.z); f[3] = (short)f2bf(u.w);
            f[4] = (short)f2bf(v.x); f[5] = (short)f2bf(v.y);
            f[6] = (short)f2bf(v.z); f[7] = (short)f2bf(v.w);
            af[mt] = f;
        }

        short8 bf[4];
        #pragma unroll
        for (int nt = 0; nt < 4; ++nt)
            bf[nt] = *(const short8*)&syT[(nt * 16 + l15) * SYT_STRIDE + k0];

        #pragma unroll
        for (int mt = 0; mt < 3; ++mt)
            #pragma unroll
            for (int nt = 0; nt < 4; ++nt)
                acc[mt][nt] = __builtin_amdgcn_mfma_f32_16x16x32_bf16(
                    af[mt], bf[nt], acc[mt][nt], 0, 0, 0);
    }

    const size_t base = (((size_t)n * COUT) << 12) + ((size_t)h << 6);
    #pragma unroll
    for (int mt = 0; mt < 3; ++mt) {
        #pragma unroll
        for (int r = 0; r < 4; ++r) {
            const int o = ob + mt * 16 + q * 4 + r;
            float s = 0.f, ss = 0.f;
            #pragma unroll
            for (int nt = 0; nt < 4; ++nt) {
                const float v = acc[mt][nt][r];
                zout[base + ((size_t)o << 12) + nt * 16 + l15] = v;
                s  += v;
                ss += v * v;
            }
            #pragma unroll
            for (int off = 8; off > 0; off >>= 1) {
                s  += __shfl_down(s,  off, 16);
                ss += __shfl_down(ss, off, 16);
            }
            if (l15 == 0) {
                atomicAdd(&ws[o], s);
                atomicAdd(&ws[COUT + o], ss);
            }
        }
    }
}

__global__ __launch_bounds__(256) void norm_kernel(
    float* __restrict__ out, const float* __restrict__ ws)
{
    const size_t i = (size_t)blockIdx.x * 256 + threadIdx.x;
    const int c = (int)((i >> 10) % COUT);
    const float sc = ws[2 * COUT + c];
    const float sh = ws[3 * COUT + c];
    float4 v = ((const float4*)out)[i];
    v.x = fmaf(v.x, sc, sh);
    v.y = fmaf(v.y, sc, sh);
    v.z = fmaf(v.z, sc, sh);
    v.w = fmaf(v.w, sc, sh);
    ((float4*)out)[i] = v;
}

// ---------------------------------------------------------------------------
extern "C" void kernel_launch(void* const* d_in, const int* in_sizes, int n_in,
                              void* d_out, int out_size, void* d_ws, size_t ws_size,
                              hipStream_t stream) {
    const float* x     = (const float*)d_in[0];
    const float* dww   = (const float*)d_in[1];
    const float* pw    = (const float*)d_in[2];
    const float* gamma = (const float*)d_in[3];
    const float* beta  = (const float*)d_in[4];
    float* out = (float*)d_out;
    float* ws  = (float*)d_ws;

    const size_t PWB_OFF = 4096;                  // bytes (past ws[0..767])
    const size_t Y_OFF   = 1u << 20;              // 1 MB
    const size_t Y_BYTES = (size_t)N_ * H_ * W_ * CIN * 2;  // 100.7 MB
    const size_t need    = Y_OFF + Y_BYTES;

    if (ws_size >= need) {
        unsigned short* pwb = (unsigned short*)((char*)d_ws + PWB_OFF);
        unsigned short* y   = (unsigned short*)((char*)d_ws + Y_OFF);

        init_ws<<<145, 256, 0, stream>>>(pw, ws, pwb);
        dw_kernel<<<N_ * H_, 256, 0, stream>>>(x, dww, y);
        gemm_kernel<<<N_ * H_, 256, 0, stream>>>(y, pwb, out, ws);
        stats_kernel<<<1, 256, 0, stream>>>(gamma, beta, ws);
        norm2_kernel<<<N_ * COUT, 256, 0, stream>>>(out, ws);
    } else {
        // Fallback: previous verified single-fused-kernel path
        zero_ws<<<1, 384, 0, stream>>>(ws);
        fused_kernel<<<N_ * H_, 256, 0, stream>>>(x, dww, pw, out, ws);
        stats_kernel<<<1, 256, 0, stream>>>(gamma, beta, ws);
        norm_kernel<<<49152, 256, 0, stream>>>(out, ws);
    }
}

// Round 3
// 610.362 us; speedup vs baseline: 1.5831x; 1.5831x over previous
//
#include <hip/hip_runtime.h>

#define N_    64
#define CIN   192
#define COUT  192
#define H_    64
#define W_    64
#define BN_EPS 1e-5f
#define M_    262144.0f              // N*H*W
#define SYT_STRIDE 200               // bf16 elems per pixel row (192 + 8 pad)
#define NCOPY 64                     // spread factor for stats atomics

typedef __attribute__((ext_vector_type(8))) short  short8;
typedef __attribute__((ext_vector_type(4))) float  floatx4;

__device__ __forceinline__ unsigned short f2bf(float f) {
    union { float f; unsigned int u; } v; v.f = f;
    unsigned int u = v.u;
    return (unsigned short)((u + 0x7FFFu + ((u >> 16) & 1u)) >> 16);  // RNE
}

// ws float layout:
//   [384..575] scale, [576..767] shift
//   [32768 .. 32768+NCOPY*384) spread BN accumulators (sum | sumsq per copy)
// bytes [4096 .. 4096+73728) : pwb (bf16 pw)
#define SC_OFF 384
#define SH_OFF 576
#define CP_OFF 32768

// ---------------------------------------------------------------------------
// Init: blocks 0..143 convert pw fp32 -> bf16; blocks 144..239 zero the
// spread accumulators (NCOPY*384 = 24576 floats).
// ---------------------------------------------------------------------------
__global__ __launch_bounds__(256) void init_ws(
    const float* __restrict__ pw, float* __restrict__ ws,
    unsigned short* __restrict__ pwb)
{
    const int b = blockIdx.x, t = threadIdx.x;
    if (b < 144) {
        const int i = b * 256 + t;
        pwb[i] = f2bf(pw[i]);
    } else {
        const int i = (b - 144) * 256 + t;        // 0..24575
        ws[CP_OFF + i] = 0.f;
    }
}

// ---------------------------------------------------------------------------
// K1: ReLU + depthwise dilated conv -> y bf16 NHWC [n][h][w][c].
// One block per (n,h) row, 256 threads. Taps via shfl. XCD-swizzled.
// ---------------------------------------------------------------------------
__global__ __launch_bounds__(256) void dw_kernel(
    const float* __restrict__ x, const float* __restrict__ dww,
    unsigned short* __restrict__ y)
{
    __shared__ float sdw[CIN * 9];                // 6.9 KB

    const int t   = threadIdx.x;
    const int bid = blockIdx.x;
    const int wg  = ((bid & 7) << 9) | (bid >> 3);   // bijective, 4096 % 8 == 0
    const int n   = wg >> 6;
    const int h   = wg & 63;

    for (int i = t; i < CIN * 9; i += 256) sdw[i] = dww[i];

    const int  w    = t & 63;                     // wave = lanes w 0..63 exactly
    const int  cblk = t >> 6;                     // wave id 0..3
    const bool wm0  = (w >= 2);
    const bool wm2  = (w <= 61);
    __syncthreads();

    const int h0 = h - 2;
    for (int e = 0; e < 6; ++e) {
        const int cb = (cblk + (e << 2)) << 3;    // channel base (multiple of 8)
        float a[8];
        #pragma unroll
        for (int ci = 0; ci < 8; ++ci) {
            const int c = cb + ci;
            const float* xp = x + (((size_t)(n * CIN + c)) << 12) + w;
            const float* kw = &sdw[c * 9];
            float acc = 0.f;
            #pragma unroll
            for (int dh = 0; dh < 3; ++dh) {
                const int hh = h0 + (dh << 1);
                if ((unsigned)hh < 64u) {         // uniform per block
                    float v1 = fmaxf(xp[hh << 6], 0.f);
                    float v0 = __shfl_up(v1, 2, 64);
                    float v2 = __shfl_down(v1, 2, 64);
                    v0 = wm0 ? v0 : 0.f;
                    v2 = wm2 ? v2 : 0.f;
                    acc = fmaf(v0, kw[3 * dh + 0], acc);
                    acc = fmaf(v1, kw[3 * dh + 1], acc);
                    acc = fmaf(v2, kw[3 * dh + 2], acc);
                }
            }
            a[ci] = acc;
        }
        uint4 pk;
        pk.x = (unsigned)f2bf(a[0]) | ((unsigned)f2bf(a[1]) << 16);
        pk.y = (unsigned)f2bf(a[2]) | ((unsigned)f2bf(a[3]) << 16);
        pk.z = (unsigned)f2bf(a[4]) | ((unsigned)f2bf(a[5]) << 16);
        pk.w = (unsigned)f2bf(a[6]) | ((unsigned)f2bf(a[7]) << 16);
        *(uint4*)&y[(size_t)wg * 12288 + (size_t)w * 192 + cb] = pk;
    }
}

// ---------------------------------------------------------------------------
// K2: pointwise GEMM (bf16 MFMA) -> BN stats ONLY (no z store).
// Stats go to spread copy (wg & 63) -> atomic chain length 64 instead of 4096.
// ---------------------------------------------------------------------------
__global__ __launch_bounds__(256) void gemm_stats_kernel(
    const unsigned short* __restrict__ y, const unsigned short* __restrict__ pwb,
    float* __restrict__ ws)
{
    __shared__ unsigned short syT[W_ * SYT_STRIDE]; // 25.6 KB [pix][c] bf16

    const int t  = threadIdx.x;
    const int wg = blockIdx.x;                    // n*64 + h

    // ---- Stage y tile (contiguous 1536 x 16B) into padded LDS ----
    const size_t ybase = (size_t)wg * 12288;
    #pragma unroll
    for (int it = 0; it < 6; ++it) {
        const int idx = it * 256 + t;             // 0..1535
        const int px  = idx / 24;
        const int cb  = (idx % 24) << 3;
        uint4 v = *(const uint4*)&y[ybase + (size_t)idx * 8];
        *(uint4*)&syT[px * SYT_STRIDE + cb] = v;
    }
    __syncthreads();

    const int wv   = t >> 6;
    const int lane = t & 63;
    const int l15  = lane & 15;
    const int q    = lane >> 4;
    const int ob   = wv * 48;

    floatx4 acc[3][4];
    #pragma unroll
    for (int mt = 0; mt < 3; ++mt)
        #pragma unroll
        for (int nt = 0; nt < 4; ++nt) acc[mt][nt] = (floatx4)0.f;

    #pragma unroll
    for (int kk = 0; kk < 6; ++kk) {
        const int k0 = kk * 32 + q * 8;

        short8 af[3];
        #pragma unroll
        for (int mt = 0; mt < 3; ++mt)
            af[mt] = *(const short8*)&pwb[(size_t)(ob + mt * 16 + l15) * CIN + k0];

        short8 bf[4];
        #pragma unroll
        for (int nt = 0; nt < 4; ++nt)
            bf[nt] = *(const short8*)&syT[(nt * 16 + l15) * SYT_STRIDE + k0];

        #pragma unroll
        for (int mt = 0; mt < 3; ++mt)
            #pragma unroll
            for (int nt = 0; nt < 4; ++nt)
                acc[mt][nt] = __builtin_amdgcn_mfma_f32_16x16x32_bf16(
                    af[mt], bf[nt], acc[mt][nt], 0, 0, 0);
    }

    // ---- Stats epilogue: per-channel sum/sumsq -> spread atomic copy ----
    float* cp = ws + CP_OFF + (size_t)(wg & (NCOPY - 1)) * 384;
    #pragma unroll
    for (int mt = 0; mt < 3; ++mt) {
        #pragma unroll
        for (int r = 0; r < 4; ++r) {
            const int o = ob + mt * 16 + q * 4 + r;
            float s = 0.f, ss = 0.f;
            #pragma unroll
            for (int nt = 0; nt < 4; ++nt) {
                const float v = acc[mt][nt][r];
                s  += v;
                ss += v * v;
            }
            #pragma unroll
            for (int off = 8; off > 0; off >>= 1) {
                s  += __shfl_down(s,  off, 16);
                ss += __shfl_down(ss, off, 16);
            }
            if (l15 == 0) {
                atomicAdd(&cp[o], s);
                atomicAdd(&cp[192 + o], ss);
            }
        }
    }
}

// ---------------------------------------------------------------------------
// Stats fold: reduce NCOPY spread copies -> per-channel scale/shift
// ---------------------------------------------------------------------------
__global__ __launch_bounds__(256) void stats2_kernel(
    const float* __restrict__ gamma, const float* __restrict__ beta,
    float* __restrict__ ws)
{
    int t = threadIdx.x;
    if (t < COUT) {
        float s = 0.f, ss = 0.f;
        for (int k = 0; k < NCOPY; ++k) {
            s  += ws[CP_OFF + k * 384 + t];
            ss += ws[CP_OFF + k * 384 + 192 + t];
        }
        const float invM = 1.0f / M_;
        float m    = s * invM;
        float v    = ss * invM - m * m;
        float rstd = rsqrtf(v + BN_EPS);
        float sc   = gamma[t] * rstd;
        ws[SC_OFF + t] = sc;
        ws[SH_OFF + t] = beta[t] - m * sc;
    }
}

// ---------------------------------------------------------------------------
// K3: recompute GEMM from y (bit-identical z) and write NORMALIZED output.
// No atomics, no stats, no z round-trip.
// ---------------------------------------------------------------------------
__global__ __launch_bounds__(256) void gemm_norm_kernel(
    const unsigned short* __restrict__ y, const unsigned short* __restrict__ pwb,
    const float* __restrict__ ws, float* __restrict__ out)
{
    __shared__ unsigned short syT[W_ * SYT_STRIDE];

    const int t  = threadIdx.x;
    const int wg = blockIdx.x;                    // n*64 + h
    const int n  = wg >> 6;
    const int h  = wg & 63;

    const size_t ybase = (size_t)wg * 12288;
    #pragma unroll
    for (int it = 0; it < 6; ++it) {
        const int idx = it * 256 + t;
        const int px  = idx / 24;
        const int cb  = (idx % 24) << 3;
        uint4 v = *(const uint4*)&y[ybase + (size_t)idx * 8];
        *(uint4*)&syT[px * SYT_STRIDE + cb] = v;
    }
    __syncthreads();

    const int wv   = t >> 6;
    const int lane = t & 63;
    const int l15  = lane & 15;
    const int q    = lane >> 4;
    const int ob   = wv * 48;

    floatx4 acc[3][4];
    #pragma unroll
    for (int mt = 0; mt < 3; ++mt)
        #pragma unroll
        for (int nt = 0; nt < 4; ++nt) acc[mt][nt] = (floatx4)0.f;

    #pragma unroll
    for (int kk = 0; kk < 6; ++kk) {
        const int k0 = kk * 32 + q * 8;

        short8 af[3];
        #pragma unroll
        for (int mt = 0; mt < 3; ++mt)
            af[mt] = *(const short8*)&pwb[(size_t)(ob + mt * 16 + l15) * CIN + k0];

        short8 bf[4];
        #pragma unroll
        for (int nt = 0; nt < 4; ++nt)
            bf[nt] = *(const short8*)&syT[(nt * 16 + l15) * SYT_STRIDE + k0];

        #pragma unroll
        for (int mt = 0; mt < 3; ++mt)
            #pragma unroll
            for (int nt = 0; nt < 4; ++nt)
                acc[mt][nt] = __builtin_amdgcn_mfma_f32_16x16x32_bf16(
                    af[mt], bf[nt], acc[mt][nt], 0, 0, 0);
    }

    // ---- Epilogue: normalize in registers, store out ----
    const size_t base = (((size_t)n * COUT) << 12) + ((size_t)h << 6);
    #pragma unroll
    for (int mt = 0; mt < 3; ++mt) {
        #pragma unroll
        for (int r = 0; r < 4; ++r) {
            const int o  = ob + mt * 16 + q * 4 + r;
            const float sc = ws[SC_OFF + o];
            const float sh = ws[SH_OFF + o];
            #pragma unroll
            for (int nt = 0; nt < 4; ++nt) {
                const float v = fmaf(acc[mt][nt][r], sc, sh);
                out[base + ((size_t)o << 12) + nt * 16 + l15] = v;
            }
        }
    }
}

// ===========================================================================
// Fallback path (verified round-0 kernel) — used only if ws_size too small.
// ===========================================================================
__global__ __launch_bounds__(384) void zero_ws(float* __restrict__ ws) {
    int t = threadIdx.x;
    if (t < 384) ws[t] = 0.f;
}

__global__ __launch_bounds__(256) void stats_kernel(
    const float* __restrict__ gamma, const float* __restrict__ beta,
    float* __restrict__ ws)
{
    int t = threadIdx.x;
    if (t < COUT) {
        const float invM = 1.0f / M_;
        float m    = ws[t] * invM;
        float v    = ws[COUT + t] * invM - m * m;
        float rstd = rsqrtf(v + BN_EPS);
        float sc   = gamma[t] * rstd;
        ws[2 * COUT + t] = sc;
        ws[3 * COUT + t] = beta[t] - m * sc;
    }
}

__global__ __launch_bounds__(256, 4) void fused_kernel(
    const float* __restrict__ x, const float* __restrict__ dww,
    const float* __restrict__ pw, float* __restrict__ zout,
    float* __restrict__ ws)
{
    __shared__ float  sdw[CIN * 9];
    __shared__ unsigned short syT[W_ * SYT_STRIDE];

    const int t = threadIdx.x;
    const int n = blockIdx.x >> 6;
    const int h = blockIdx.x & 63;

    for (int i = t; i < CIN * 9; i += 256) sdw[i] = dww[i];

    const int  w    = t & 63;
    const int  cblk = t >> 6;
    const bool wm0  = (w >= 2);
    const bool wm2  = (w <= 61);
    const int  om   = wm0 ? -2 : 0;
    const int  op   = wm2 ?  2 : 0;
    __syncthreads();

    for (int e = 0; e < 6; ++e) {
        const int cb = (cblk + (e << 2)) << 3;
        float a[8];
        #pragma unroll
        for (int ci = 0; ci < 8; ++ci) {
            const int c = cb + ci;
            const float* xr0 = x + (((size_t)(n * CIN + c)) << 12) + w;
            const float* kw  = &sdw[c * 9];
            float acc = 0.f;
            #pragma unroll
            for (int dh = 0; dh < 3; ++dh) {
                const int hh = h + 2 * dh - 2;
                if ((unsigned)hh < 64u) {
                    const float* xr = xr0 + (hh << 6);
                    float v0 = fmaxf(xr[om], 0.f);
                    float v1 = fmaxf(xr[0],  0.f);
                    float v2 = fmaxf(xr[op], 0.f);
                    v0 = wm0 ? v0 : 0.f;
                    v2 = wm2 ? v2 : 0.f;
                    acc = fmaf(v0, kw[3 * dh + 0], acc);
                    acc = fmaf(v1, kw[3 * dh + 1], acc);
                    acc = fmaf(v2, kw[3 * dh + 2], acc);
                }
            }
            a[ci] = acc;
        }
        uint4 pk;
        pk.x = (unsigned)f2bf(a[0]) | ((unsigned)f2bf(a[1]) << 16);
        pk.y = (unsigned)f2bf(a[2]) | ((unsigned)f2bf(a[3]) << 16);
        pk.z = (unsigned)f2bf(a[4]) | ((unsigned)f2bf(a[5]) << 16);
        pk.w = (unsigned)f2bf(a[6]) | ((unsigned)f2bf(a[7]) << 16);
        *(uint4*)&syT[w * SYT_STRIDE + cb] = pk;
    }
    __syncthreads();

    const int wv   = t >> 6;
    const int lane = t & 63;
    const int l15  = lane & 15;
    const int q    = lane >> 4;
    const int ob   = wv * 48;

    floatx4 acc[3][4];
    #pragma unroll
    for (int mt = 0; mt < 3; ++mt)
        #pragma unroll
        for (int nt = 0; nt < 4; ++nt) acc[mt][nt] = (floatx4)0.f;

    #pragma unroll
    for (int kk = 0; kk < 6; ++kk) {
        const int k0 = kk * 32 + q * 8;

        short8 af[3];
        #pragma unroll
        for (int mt = 0; mt < 3; ++mt) {
            const float4* ap = (const float4*)(pw + (size_t)(ob + mt * 16 + l15) * CIN + k0);
            float4 u = ap[0];
            float4 v = ap[1];
            short8 f;
            f[0] = (short)f2bf(u.x); f[1] = (short)f2bf(u.y);
            f[2] = (short)f2bf(u.z); f[3] = (short)f2bf(u.w);
            f[4] = (short)f2bf(v.x); f[5] = (short)f2bf(v.y);
            f[6] = (short)f2bf(v.z); f[7] = (short)f2bf(v.w);
            af[mt] = f;
        }

        short8 bf[4];
        #pragma unroll
        for (int nt = 0; nt < 4; ++nt)
            bf[nt] = *(const short8*)&syT[(nt * 16 + l15) * SYT_STRIDE + k0];

        #pragma unroll
        for (int mt = 0; mt < 3; ++mt)
            #pragma unroll
            for (int nt = 0; nt < 4; ++nt)
                acc[mt][nt] = __builtin_amdgcn_mfma_f32_16x16x32_bf16(
                    af[mt], bf[nt], acc[mt][nt], 0, 0, 0);
    }

    const size_t base = (((size_t)n * COUT) << 12) + ((size_t)h << 6);
    #pragma unroll
    for (int mt = 0; mt < 3; ++mt) {
        #pragma unroll
        for (int r = 0; r < 4; ++r) {
            const int o = ob + mt * 16 + q * 4 + r;
            float s = 0.f, ss = 0.f;
            #pragma unroll
            for (int nt = 0; nt < 4; ++nt) {
                const float v = acc[mt][nt][r];
                zout[base + ((size_t)o << 12) + nt * 16 + l15] = v;
                s  += v;
                ss += v * v;
            }
            #pragma unroll
            for (int off = 8; off > 0; off >>= 1) {
                s  += __shfl_down(s,  off, 16);
                ss += __shfl_down(ss, off, 16);
            }
            if (l15 == 0) {
                atomicAdd(&ws[o], s);
                atomicAdd(&ws[COUT + o], ss);
            }
        }
    }
}

__global__ __launch_bounds__(256) void norm_kernel(
    float* __restrict__ out, const float* __restrict__ ws)
{
    const size_t i = (size_t)blockIdx.x * 256 + threadIdx.x;
    const int c = (int)((i >> 10) % COUT);
    const float sc = ws[2 * COUT + c];
    const float sh = ws[3 * COUT + c];
    float4 v = ((const float4*)out)[i];
    v.x = fmaf(v.x, sc, sh);
    v.y = fmaf(v.y, sc, sh);
    v.z = fmaf(v.z, sc, sh);
    v.w = fmaf(v.w, sc, sh);
    ((float4*)out)[i] = v;
}

// ---------------------------------------------------------------------------
extern "C" void kernel_launch(void* const* d_in, const int* in_sizes, int n_in,
                              void* d_out, int out_size, void* d_ws, size_t ws_size,
                              hipStream_t stream) {
    const float* x     = (const float*)d_in[0];
    const float* dww   = (const float*)d_in[1];
    const float* pw    = (const float*)d_in[2];
    const float* gamma = (const float*)d_in[3];
    const float* beta  = (const float*)d_in[4];
    float* out = (float*)d_out;
    float* ws  = (float*)d_ws;

    const size_t PWB_OFF = 4096;                  // bytes (floats 0..1023 reserved)
    const size_t Y_OFF   = 1u << 20;              // 1 MB
    const size_t Y_BYTES = (size_t)N_ * H_ * W_ * CIN * 2;  // 100.7 MB
    const size_t need    = Y_OFF + Y_BYTES;

    if (ws_size >= need) {
        unsigned short* pwb = (unsigned short*)((char*)d_ws + PWB_OFF);
        unsigned short* y   = (unsigned short*)((char*)d_ws + Y_OFF);

        init_ws<<<240, 256, 0, stream>>>(pw, ws, pwb);
        dw_kernel<<<N_ * H_, 256, 0, stream>>>(x, dww, y);
        gemm_stats_kernel<<<N_ * H_, 256, 0, stream>>>(y, pwb, ws);
        stats2_kernel<<<1, 256, 0, stream>>>(gamma, beta, ws);
        gemm_norm_kernel<<<N_ * H_, 256, 0, stream>>>(y, pwb, ws, out);
    } else {
        // Fallback: verified single-fused-kernel path
        zero_ws<<<1, 384, 0, stream>>>(ws);
        fused_kernel<<<N_ * H_, 256, 0, stream>>>(x, dww, pw, out, ws);
        stats_kernel<<<1, 256, 0, stream>>>(gamma, beta, ws);
        norm_kernel<<<49152, 256, 0, stream>>>(out, ws);
    }
}

// Round 5
// 490.530 us; speedup vs baseline: 1.9698x; 1.2443x over previous
//
#include <hip/hip_runtime.h>

#define N_    64
#define CIN   192
#define COUT  192
#define H_    64
#define W_    64
#define BN_EPS 1e-5f
#define M_    262144.0f              // N*H*W
#define SYT_STRIDE 200               // bf16 elems per pixel row (192 + 8 pad)
#define NCOPY 64                     // spread factor for stats atomics

typedef __attribute__((ext_vector_type(8))) short  short8;
typedef __attribute__((ext_vector_type(4))) float  floatx4;

__device__ __forceinline__ unsigned short f2bf(float f) {
    union { float f; unsigned int u; } v; v.f = f;
    unsigned int u = v.u;
    return (unsigned short)((u + 0x7FFFu + ((u >> 16) & 1u)) >> 16);  // RNE
}

// ws float layout:
//   [384..575] scale, [576..767] shift
//   [32768 .. 32768+NCOPY*384) spread BN accumulators (sum | sumsq per copy)
// bytes [4096 .. 4096+73728) : pwb (bf16 pw)
#define SC_OFF 384
#define SH_OFF 576
#define CP_OFF 32768

// ---------------------------------------------------------------------------
// Init: blocks 0..143 convert pw fp32 -> bf16; blocks 144..239 zero the
// spread accumulators (NCOPY*384 = 24576 floats).
// ---------------------------------------------------------------------------
__global__ __launch_bounds__(256) void init_ws(
    const float* __restrict__ pw, float* __restrict__ ws,
    unsigned short* __restrict__ pwb)
{
    const int b = blockIdx.x, t = threadIdx.x;
    if (b < 144) {
        const int i = b * 256 + t;
        pwb[i] = f2bf(pw[i]);
    } else {
        const int i = (b - 144) * 256 + t;        // 0..24575
        ws[CP_OFF + i] = 0.f;
    }
}

// ---------------------------------------------------------------------------
// K1 (rewritten): streaming ReLU + depthwise dilated conv.
// Block = (channel-group cg of 8, image n); thread = (w, 2 channels).
// Streams h with two parity rolling windows (taps h-2,h,h+2): each x element
// loaded EXACTLY once, branch-free steady loop, loads prefetched 1 iter ahead.
// Output y layout (group-blocked): tile wg=[n*64+h] of 12288 bf16 elems as
// [24 g][64 w][8 c]; staged 8 rows in LDS, flushed with coalesced 16B stores.
// ---------------------------------------------------------------------------
#define PROC(vraw, t0, t1, t2) do {                    \
    float _v = fmaxf((vraw), 0.f);                     \
    float _u = __shfl_up(_v, 2, 64);                   \
    float _d = __shfl_down(_v, 2, 64);                 \
    (t0) = wm0 ? _u : 0.f;                             \
    (t1) = _v;                                         \
    (t2) = wm2 ? _d : 0.f; } while (0)

__global__ __launch_bounds__(256) void dw_kernel(
    const float* __restrict__ x, const float* __restrict__ dww,
    unsigned short* __restrict__ y)
{
    __shared__ unsigned short sy[8 * 512];        // 8 rows x 64 w x 8 c, 8 KB

    const int t     = threadIdx.x;
    const int w     = t & 63;                     // lane = w
    const int cpair = t >> 6;                     // wave id 0..3
    const int cg    = blockIdx.x;                 // 0..23 channel group
    const int n     = blockIdx.y;                 // 0..63 image
    const bool wm0  = (w >= 2);
    const bool wm2  = (w <= 61);

    const int c0 = cg * 8 + cpair * 2;            // this thread's 2 channels

    float kw[2][9];
    #pragma unroll
    for (int ch = 0; ch < 2; ++ch)
        #pragma unroll
        for (int i = 0; i < 9; ++i)
            kw[ch][i] = dww[(c0 + ch) * 9 + i];

    const float* xp[2];
    xp[0] = x + (((size_t)(n * CIN + c0)) << 12) + w;
    xp[1] = xp[0] + 4096;

    // Parity windows: P = even rows, Q = odd rows. Triples = (w-2, w, w+2).
    float Pm[2][3], Pc[2][3], Pn[2][3], Qm[2][3], Qc[2][3], Qn[2][3];
    float r0[2], r1[2];                           // raw rows 2k+4, 2k+5

    #pragma unroll
    for (int ch = 0; ch < 2; ++ch) {
        Pm[ch][0] = Pm[ch][1] = Pm[ch][2] = 0.f;  // row -2
        Qm[ch][0] = Qm[ch][1] = Qm[ch][2] = 0.f;  // row -1
        float x0 = xp[ch][0];
        float x1 = xp[ch][64];
        float x2 = xp[ch][128];
        float x3 = xp[ch][192];
        r0[ch]   = xp[ch][256];                   // row 4
        r1[ch]   = xp[ch][320];                   // row 5
        PROC(x0, Pc[ch][0], Pc[ch][1], Pc[ch][2]);
        PROC(x1, Qc[ch][0], Qc[ch][1], Qc[ch][2]);
        PROC(x2, Pn[ch][0], Pn[ch][1], Pn[ch][2]);
        PROC(x3, Qn[ch][0], Qn[ch][1], Qn[ch][2]);
    }

    const size_t tile0 = (size_t)(n * 64) * 12288 + (size_t)cg * 512;

    #pragma unroll 4
    for (int k = 0; k < 32; ++k) {
        // 1. prefetch rows 2k+6, 2k+7 (uniform bounds check; only tail masks)
        const int ra = 2 * k + 6, rb = 2 * k + 7;
        float n0[2], n1[2];
        #pragma unroll
        for (int ch = 0; ch < 2; ++ch) {
            n0[ch] = (ra < 64) ? xp[ch][ra << 6] : 0.f;
            n1[ch] = (rb < 64) ? xp[ch][rb << 6] : 0.f;
        }

        // 2. emit outputs h = 2k (from P) and h = 2k+1 (from Q)
        float oa[2], ob[2];
        #pragma unroll
        for (int ch = 0; ch < 2; ++ch) {
            float a = 0.f;
            a = fmaf(Pm[ch][0], kw[ch][0], a);
            a = fmaf(Pm[ch][1], kw[ch][1], a);
            a = fmaf(Pm[ch][2], kw[ch][2], a);
            a = fmaf(Pc[ch][0], kw[ch][3], a);
            a = fmaf(Pc[ch][1], kw[ch][4], a);
            a = fmaf(Pc[ch][2], kw[ch][5], a);
            a = fmaf(Pn[ch][0], kw[ch][6], a);
            a = fmaf(Pn[ch][1], kw[ch][7], a);
            a = fmaf(Pn[ch][2], kw[ch][8], a);
            oa[ch] = a;
            float b = 0.f;
            b = fmaf(Qm[ch][0], kw[ch][0], b);
            b = fmaf(Qm[ch][1], kw[ch][1], b);
            b = fmaf(Qm[ch][2], kw[ch][2], b);
            b = fmaf(Qc[ch][0], kw[ch][3], b);
            b = fmaf(Qc[ch][1], kw[ch][4], b);
            b = fmaf(Qc[ch][2], kw[ch][5], b);
            b = fmaf(Qn[ch][0], kw[ch][6], b);
            b = fmaf(Qn[ch][1], kw[ch][7], b);
            b = fmaf(Qn[ch][2], kw[ch][8], b);
            ob[ch] = b;
        }
        const unsigned d0 = (unsigned)f2bf(oa[0]) | ((unsigned)f2bf(oa[1]) << 16);
        const unsigned d1 = (unsigned)f2bf(ob[0]) | ((unsigned)f2bf(ob[1]) << 16);
        const int slot = (2 * k) & 7;             // even
        const int si   = w * 8 + cpair * 2;
        *(unsigned int*)&sy[slot * 512 + si]       = d0;
        *(unsigned int*)&sy[(slot + 1) * 512 + si] = d1;

        // 3. advance windows (rows 2k+2 / 2k+3 ingested; loaded last iter)
        #pragma unroll
        for (int ch = 0; ch < 2; ++ch) {
            #pragma unroll
            for (int i = 0; i < 3; ++i) { Pm[ch][i] = Pc[ch][i]; Pc[ch][i] = Pn[ch][i]; }
            PROC(r0[ch], Pn[ch][0], Pn[ch][1], Pn[ch][2]);
            #pragma unroll
            for (int i = 0; i < 3; ++i) { Qm[ch][i] = Qc[ch][i]; Qc[ch][i] = Qn[ch][i]; }
            PROC(r1[ch], Qn[ch][0], Qn[ch][1], Qn[ch][2]);
            r0[ch] = n0[ch];
            r1[ch] = n1[ch];
        }

        // 4. every 4 iters: flush 8 rows (8 KB) coalesced
        if ((k & 3) == 3) {
            __syncthreads();
            const int hb = (k >> 2) << 3;         // first of the 8 rows
            const unsigned u0 = t, u1 = t + 256;  // uint4 index: row=u>>6, w=u&63
            uint4 v0 = *(const uint4*)&sy[u0 * 8];
            uint4 v1 = *(const uint4*)&sy[u1 * 8];
            *(uint4*)&y[tile0 + (size_t)(hb + (u0 >> 6)) * 12288 + (u0 & 63) * 8] = v0;
            *(uint4*)&y[tile0 + (size_t)(hb + (u1 >> 6)) * 12288 + (u1 & 63) * 8] = v1;
            __syncthreads();
        }
    }
}

// ---------------------------------------------------------------------------
// K2: pointwise GEMM (bf16 MFMA) -> BN stats ONLY (no z store).
// Stats go to spread copy (wg & 63) -> atomic chain length 64 instead of 4096.
// Staging index updated for the group-blocked y layout [g][w][8c].
// ---------------------------------------------------------------------------
__global__ __launch_bounds__(256) void gemm_stats_kernel(
    const unsigned short* __restrict__ y, const unsigned short* __restrict__ pwb,
    float* __restrict__ ws)
{
    __shared__ unsigned short syT[W_ * SYT_STRIDE]; // 25.6 KB [pix][c] bf16

    const int t  = threadIdx.x;
    const int wg = blockIdx.x;                    // n*64 + h

    // ---- Stage y tile (contiguous 1536 x 16B) into padded LDS ----
    const size_t ybase = (size_t)wg * 12288;
    #pragma unroll
    for (int it = 0; it < 6; ++it) {
        const int idx = it * 256 + t;             // 0..1535 = g*64 + w
        const int px  = idx & 63;                 // pixel w
        const int cb  = (idx >> 6) << 3;          // channel base g*8
        uint4 v = *(const uint4*)&y[ybase + (size_t)idx * 8];
        *(uint4*)&syT[px * SYT_STRIDE + cb] = v;
    }
    __syncthreads();

    const int wv   = t >> 6;
    const int lane = t & 63;
    const int l15  = lane & 15;
    const int q    = lane >> 4;
    const int ob   = wv * 48;

    floatx4 acc[3][4];
    #pragma unroll
    for (int mt = 0; mt < 3; ++mt)
        #pragma unroll
        for (int nt = 0; nt < 4; ++nt) acc[mt][nt] = (floatx4)0.f;

    #pragma unroll
    for (int kk = 0; kk < 6; ++kk) {
        const int k0 = kk * 32 + q * 8;

        short8 af[3];
        #pragma unroll
        for (int mt = 0; mt < 3; ++mt)
            af[mt] = *(const short8*)&pwb[(size_t)(ob + mt * 16 + l15) * CIN + k0];

        short8 bf[4];
        #pragma unroll
        for (int nt = 0; nt < 4; ++nt)
            bf[nt] = *(const short8*)&syT[(nt * 16 + l15) * SYT_STRIDE + k0];

        #pragma unroll
        for (int mt = 0; mt < 3; ++mt)
            #pragma unroll
            for (int nt = 0; nt < 4; ++nt)
                acc[mt][nt] = __builtin_amdgcn_mfma_f32_16x16x32_bf16(
                    af[mt], bf[nt], acc[mt][nt], 0, 0, 0);
    }

    // ---- Stats epilogue: per-channel sum/sumsq -> spread atomic copy ----
    float* cp = ws + CP_OFF + (size_t)(wg & (NCOPY - 1)) * 384;
    #pragma unroll
    for (int mt = 0; mt < 3; ++mt) {
        #pragma unroll
        for (int r = 0; r < 4; ++r) {
            const int o = ob + mt * 16 + q * 4 + r;
            float s = 0.f, ss = 0.f;
            #pragma unroll
            for (int nt = 0; nt < 4; ++nt) {
                const float v = acc[mt][nt][r];
                s  += v;
                ss += v * v;
            }
            #pragma unroll
            for (int off = 8; off > 0; off >>= 1) {
                s  += __shfl_down(s,  off, 16);
                ss += __shfl_down(ss, off, 16);
            }
            if (l15 == 0) {
                atomicAdd(&cp[o], s);
                atomicAdd(&cp[192 + o], ss);
            }
        }
    }
}

// ---------------------------------------------------------------------------
// Stats fold: reduce NCOPY spread copies -> per-channel scale/shift
// ---------------------------------------------------------------------------
__global__ __launch_bounds__(256) void stats2_kernel(
    const float* __restrict__ gamma, const float* __restrict__ beta,
    float* __restrict__ ws)
{
    int t = threadIdx.x;
    if (t < COUT) {
        float s = 0.f, ss = 0.f;
        for (int k = 0; k < NCOPY; ++k) {
            s  += ws[CP_OFF + k * 384 + t];
            ss += ws[CP_OFF + k * 384 + 192 + t];
        }
        const float invM = 1.0f / M_;
        float m    = s * invM;
        float v    = ss * invM - m * m;
        float rstd = rsqrtf(v + BN_EPS);
        float sc   = gamma[t] * rstd;
        ws[SC_OFF + t] = sc;
        ws[SH_OFF + t] = beta[t] - m * sc;
    }
}

// ---------------------------------------------------------------------------
// K3: recompute GEMM from y (bit-identical z) and write NORMALIZED output.
// No atomics, no stats, no z round-trip.
// ---------------------------------------------------------------------------
__global__ __launch_bounds__(256) void gemm_norm_kernel(
    const unsigned short* __restrict__ y, const unsigned short* __restrict__ pwb,
    const float* __restrict__ ws, float* __restrict__ out)
{
    __shared__ unsigned short syT[W_ * SYT_STRIDE];

    const int t  = threadIdx.x;
    const int wg = blockIdx.x;                    // n*64 + h
    const int n  = wg >> 6;
    const int h  = wg & 63;

    const size_t ybase = (size_t)wg * 12288;
    #pragma unroll
    for (int it = 0; it < 6; ++it) {
        const int idx = it * 256 + t;
        const int px  = idx & 63;
        const int cb  = (idx >> 6) << 3;
        uint4 v = *(const uint4*)&y[ybase + (size_t)idx * 8];
        *(uint4*)&syT[px * SYT_STRIDE + cb] = v;
    }
    __syncthreads();

    const int wv   = t >> 6;
    const int lane = t & 63;
    const int l15  = lane & 15;
    const int q    = lane >> 4;
    const int ob   = wv * 48;

    floatx4 acc[3][4];
    #pragma unroll
    for (int mt = 0; mt < 3; ++mt)
        #pragma unroll
        for (int nt = 0; nt < 4; ++nt) acc[mt][nt] = (floatx4)0.f;

    #pragma unroll
    for (int kk = 0; kk < 6; ++kk) {
        const int k0 = kk * 32 + q * 8;

        short8 af[3];
        #pragma unroll
        for (int mt = 0; mt < 3; ++mt)
            af[mt] = *(const short8*)&pwb[(size_t)(ob + mt * 16 + l15) * CIN + k0];

        short8 bf[4];
        #pragma unroll
        for (int nt = 0; nt < 4; ++nt)
            bf[nt] = *(const short8*)&syT[(nt * 16 + l15) * SYT_STRIDE + k0];

        #pragma unroll
        for (int mt = 0; mt < 3; ++mt)
            #pragma unroll
            for (int nt = 0; nt < 4; ++nt)
                acc[mt][nt] = __builtin_amdgcn_mfma_f32_16x16x32_bf16(
                    af[mt], bf[nt], acc[mt][nt], 0, 0, 0);
    }

    // ---- Epilogue: normalize in registers, store out ----
    const size_t base = (((size_t)n * COUT) << 12) + ((size_t)h << 6);
    #pragma unroll
    for (int mt = 0; mt < 3; ++mt) {
        #pragma unroll
        for (int r = 0; r < 4; ++r) {
            const int o  = ob + mt * 16 + q * 4 + r;
            const float sc = ws[SC_OFF + o];
            const float sh = ws[SH_OFF + o];
            #pragma unroll
            for (int nt = 0; nt < 4; ++nt) {
                const float v = fmaf(acc[mt][nt][r], sc, sh);
                out[base + ((size_t)o << 12) + nt * 16 + l15] = v;
            }
        }
    }
}

// ===========================================================================
// Fallback path (verified round-0 kernel) — used only if ws_size too small.
// ===========================================================================
__global__ __launch_bounds__(384) void zero_ws(float* __restrict__ ws) {
    int t = threadIdx.x;
    if (t < 384) ws[t] = 0.f;
}

__global__ __launch_bounds__(256) void stats_kernel(
    const float* __restrict__ gamma, const float* __restrict__ beta,
    float* __restrict__ ws)
{
    int t = threadIdx.x;
    if (t < COUT) {
        const float invM = 1.0f / M_;
        float m    = ws[t] * invM;
        float v    = ws[COUT + t] * invM - m * m;
        float rstd = rsqrtf(v + BN_EPS);
        float sc   = gamma[t] * rstd;
        ws[2 * COUT + t] = sc;
        ws[3 * COUT + t] = beta[t] - m * sc;
    }
}

__global__ __launch_bounds__(256, 4) void fused_kernel(
    const float* __restrict__ x, const float* __restrict__ dww,
    const float* __restrict__ pw, float* __restrict__ zout,
    float* __restrict__ ws)
{
    __shared__ float  sdw[CIN * 9];
    __shared__ unsigned short syT[W_ * SYT_STRIDE];

    const int t = threadIdx.x;
    const int n = blockIdx.x >> 6;
    const int h = blockIdx.x & 63;

    for (int i = t; i < CIN * 9; i += 256) sdw[i] = dww[i];

    const int  w    = t & 63;
    const int  cblk = t >> 6;
    const bool wm0  = (w >= 2);
    const bool wm2  = (w <= 61);
    const int  om   = wm0 ? -2 : 0;
    const int  op   = wm2 ?  2 : 0;
    __syncthreads();

    for (int e = 0; e < 6; ++e) {
        const int cb = (cblk + (e << 2)) << 3;
        float a[8];
        #pragma unroll
        for (int ci = 0; ci < 8; ++ci) {
            const int c = cb + ci;
            const float* xr0 = x + (((size_t)(n * CIN + c)) << 12) + w;
            const float* kwp = &sdw[c * 9];
            float acc = 0.f;
            #pragma unroll
            for (int dh = 0; dh < 3; ++dh) {
                const int hh = h + 2 * dh - 2;
                if ((unsigned)hh < 64u) {
                    const float* xr = xr0 + (hh << 6);
                    float v0 = fmaxf(xr[om], 0.f);
                    float v1 = fmaxf(xr[0],  0.f);
                    float v2 = fmaxf(xr[op], 0.f);
                    v0 = wm0 ? v0 : 0.f;
                    v2 = wm2 ? v2 : 0.f;
                    acc = fmaf(v0, kwp[3 * dh + 0], acc);
                    acc = fmaf(v1, kwp[3 * dh + 1], acc);
                    acc = fmaf(v2, kwp[3 * dh + 2], acc);
                }
            }
            a[ci] = acc;
        }
        uint4 pk;
        pk.x = (unsigned)f2bf(a[0]) | ((unsigned)f2bf(a[1]) << 16);
        pk.y = (unsigned)f2bf(a[2]) | ((unsigned)f2bf(a[3]) << 16);
        pk.z = (unsigned)f2bf(a[4]) | ((unsigned)f2bf(a[5]) << 16);
        pk.w = (unsigned)f2bf(a[6]) | ((unsigned)f2bf(a[7]) << 16);
        *(uint4*)&syT[w * SYT_STRIDE + cb] = pk;
    }
    __syncthreads();

    const int wv   = t >> 6;
    const int lane = t & 63;
    const int l15  = lane & 15;
    const int q    = lane >> 4;
    const int ob   = wv * 48;

    floatx4 acc[3][4];
    #pragma unroll
    for (int mt = 0; mt < 3; ++mt)
        #pragma unroll
        for (int nt = 0; nt < 4; ++nt) acc[mt][nt] = (floatx4)0.f;

    #pragma unroll
    for (int kk = 0; kk < 6; ++kk) {
        const int k0 = kk * 32 + q * 8;

        short8 af[3];
        #pragma unroll
        for (int mt = 0; mt < 3; ++mt) {
            const float4* ap = (const float4*)(pw + (size_t)(ob + mt * 16 + l15) * CIN + k0);
            float4 u = ap[0];
            float4 v = ap[1];
            short8 f;
            f[0] = (short)f2bf(u.x); f[1] = (short)f2bf(u.y);
            f[2] = (short)f2bf(u.z); f[3] = (short)f2bf(u.w);
            f[4] = (short)f2bf(v.x); f[5] = (short)f2bf(v.y);
            f[6] = (short)f2bf(v.z); f[7] = (short)f2bf(v.w);
            af[mt] = f;
        }

        short8 bf[4];
        #pragma unroll
        for (int nt = 0; nt < 4; ++nt)
            bf[nt] = *(const short8*)&syT[(nt * 16 + l15) * SYT_STRIDE + k0];

        #pragma unroll
        for (int mt = 0; mt < 3; ++mt)
            #pragma unroll
            for (int nt = 0; nt < 4; ++nt)
                acc[mt][nt] = __builtin_amdgcn_mfma_f32_16x16x32_bf16(
                    af[mt], bf[nt], acc[mt][nt], 0, 0, 0);
    }

    const size_t base = (((size_t)n * COUT) << 12) + ((size_t)h << 6);
    #pragma unroll
    for (int mt = 0; mt < 3; ++mt) {
        #pragma unroll
        for (int r = 0; r < 4; ++r) {
            const int o = ob + mt * 16 + q * 4 + r;
            float s = 0.f, ss = 0.f;
            #pragma unroll
            for (int nt = 0; nt < 4; ++nt) {
                const float v = acc[mt][nt][r];
                zout[base + ((size_t)o << 12) + nt * 16 + l15] = v;
                s  += v;
                ss += v * v;
            }
            #pragma unroll
            for (int off = 8; off > 0; off >>= 1) {
                s  += __shfl_down(s,  off, 16);
                ss += __shfl_down(ss, off, 16);
            }
            if (l15 == 0) {
                atomicAdd(&ws[o], s);
                atomicAdd(&ws[COUT + o], ss);
            }
        }
    }
}

__global__ __launch_bounds__(256) void norm_kernel(
    float* __restrict__ out, const float* __restrict__ ws)
{
    const size_t i = (size_t)blockIdx.x * 256 + threadIdx.x;
    const int c = (int)((i >> 10) % COUT);
    const float sc = ws[2 * COUT + c];
    const float sh = ws[3 * COUT + c];
    float4 v = ((const float4*)out)[i];
    v.x = fmaf(v.x, sc, sh);
    v.y = fmaf(v.y, sc, sh);
    v.z = fmaf(v.z, sc, sh);
    v.w = fmaf(v.w, sc, sh);
    ((float4*)out)[i] = v;
}

// ---------------------------------------------------------------------------
extern "C" void kernel_launch(void* const* d_in, const int* in_sizes, int n_in,
                              void* d_out, int out_size, void* d_ws, size_t ws_size,
                              hipStream_t stream) {
    const float* x     = (const float*)d_in[0];
    const float* dww   = (const float*)d_in[1];
    const float* pw    = (const float*)d_in[2];
    const float* gamma = (const float*)d_in[3];
    const float* beta  = (const float*)d_in[4];
    float* out = (float*)d_out;
    float* ws  = (float*)d_ws;

    const size_t PWB_OFF = 4096;                  // bytes (floats 0..1023 reserved)
    const size_t Y_OFF   = 1u << 20;              // 1 MB
    const size_t Y_BYTES = (size_t)N_ * H_ * W_ * CIN * 2;  // 100.7 MB
    const size_t need    = Y_OFF + Y_BYTES;

    if (ws_size >= need) {
        unsigned short* pwb = (unsigned short*)((char*)d_ws + PWB_OFF);
        unsigned short* y   = (unsigned short*)((char*)d_ws + Y_OFF);

        init_ws<<<240, 256, 0, stream>>>(pw, ws, pwb);
        dw_kernel<<<dim3(24, 64), 256, 0, stream>>>(x, dww, y);
        gemm_stats_kernel<<<N_ * H_, 256, 0, stream>>>(y, pwb, ws);
        stats2_kernel<<<1, 256, 0, stream>>>(gamma, beta, ws);
        gemm_norm_kernel<<<N_ * H_, 256, 0, stream>>>(y, pwb, ws, out);
    } else {
        // Fallback: verified single-fused-kernel path
        zero_ws<<<1, 384, 0, stream>>>(ws);
        fused_kernel<<<N_ * H_, 256, 0, stream>>>(x, dww, pw, out, ws);
        stats_kernel<<<1, 256, 0, stream>>>(gamma, beta, ws);
        norm_kernel<<<49152, 256, 0, stream>>>(out, ws);
    }
}